// Round 8
// baseline (266.256 us; speedup 1.0000x reference)
//
#include <hip/hip_runtime.h>

// Round-13: 1 KB-chunk probe — the last untested point in the chunk-width
// design space.
// Round-12 post-mortem: linear two-pass A+B ~= 105 us >= 85 us falsifier ->
// paying a second x pass can never beat the 83 us strided single-pass.
// Standing: strided single-pass 83-88 us @ ~2.4 TB/s for chunk widths 64 B
// (r6), 128 B (r5), 256 B (r11) -- FLAT. But all tested chunks are only 1-2
// cache lines per DRAM page visit. This kernel: 1 KB chunks (8 x 128 B lines
// per instruction batch, same page) = genuinely different regime for
// activate amortization.
//   wave owns a 1 KB-wide x H strip (lane = one float4 column);
//   4 strips/image x 32 images = 128 one-wave blocks;
//   buf[32] float4 register prefetch = 32 KB/wave in flight
//   (128 waves x 32 KB = 4 MB of reads -> ~5 TB/s Little's-law ceiling).
// Same verified r11 skeleton: D=32 divides H (r10's OOB bug class is
// static_assert'ed away), zero sync, zero LDS, x read once, out written
// once, stores fire-and-forget.
// Pre-committed: if this lands >= 78 us at ~2.4 TB/s, chunk width 64B->1KB
// is irrelevant, the strided cap is hard -> restore r11 (83 us) and declare
// roofline next round.

constexpr int B = 32;
constexpr int H = 1024;
constexpr int W = 1024;            // floats per row
constexpr int R4 = W / 4;          // 256 float4 per row (4 KB)
constexpr int SW4 = 64;            // strip width: 64 float4 = 1 KB
constexpr int NSTRIP = R4 / SW4;   // 4 strips per image
constexpr int NBLK = B * NSTRIP;   // 128 one-wave blocks
constexpr int D = 32;              // rows in flight; MUST divide H
static_assert(H % D == 0, "D must divide H");

__device__ __forceinline__ float4 max4(float4 a, float4 b) {
    return make_float4(fmaxf(a.x, b.x), fmaxf(a.y, b.y),
                       fmaxf(a.z, b.z), fmaxf(a.w, b.w));
}

__global__ __launch_bounds__(64) void cummax_wide(const float* __restrict__ x,
                                                  float* __restrict__ o) {
    const int sid = blockIdx.x;
    const int b = sid >> 2;             // image
    const int st = sid & (NSTRIP - 1);  // strip within row
    const int lane = threadIdx.x;       // float4 column within strip

    const size_t base = (size_t)b * H * R4 + (size_t)st * SW4 + lane;
    const float4* xp = (const float4*)x + base;
    float4* op = (float4*)o + base;

    const float ninf = -__builtin_inff();
    float4 carry = make_float4(ninf, ninf, ninf, ninf);
    float4 buf[D];

    // prologue: rows 0..D-1 in flight
#pragma unroll
    for (int r = 0; r < D; ++r) buf[r] = xp[(size_t)r * R4];

    // main: consume D rows, prefetch next D (all buf indices static)
    int hb = 0;
    for (; hb < H - D; hb += D) {
        const float4* xn = xp + (size_t)(hb + D) * R4;
        float4* on = op + (size_t)hb * R4;
#pragma unroll
        for (int r = 0; r < D; ++r) {
            float4 v = buf[r];
            buf[r] = xn[(size_t)r * R4];     // prefetch row hb+D+r
            carry = max4(carry, v);
            on[(size_t)r * R4] = carry;      // store row hb+r
        }
    }

    // epilogue: last D rows (already in buf)
    {
        float4* on = op + (size_t)hb * R4;
#pragma unroll
        for (int r = 0; r < D; ++r) {
            carry = max4(carry, buf[r]);
            on[(size_t)r * R4] = carry;
        }
    }
}

extern "C" void kernel_launch(void* const* d_in, const int* in_sizes, int n_in,
                              void* d_out, int out_size, void* d_ws, size_t ws_size,
                              hipStream_t stream) {
    const float* x = (const float*)d_in[0];
    float* out = (float*)d_out;
    cummax_wide<<<NBLK, 64, 0, stream>>>(x, out);
}

// Round 9
// 234.919 us; speedup vs baseline: 1.1334x; 1.1334x over previous
//
#include <hip/hip_runtime.h>

// Round-14: RESTORE of round-11's cummax_stream — the best verified kernel
// (83.2 us dispatch / 236.2 us bench, absmax 0.0).
// Round-13 post-mortem: 1 KB chunks regressed to 107 us @ 1.87 TB/s ->
// chunk-width space fully mapped: 64B/128B/256B/1KB = 2.33/2.29/2.42/1.87
// TB/s. The strided column-walk cap (~2.4 TB/s) is flat across footprint,
// wave count (128-4096), barriers, and prefetch depth. Linear-traversal
// alternatives measured: two-pass ~105 us (second x pass), grid.sync 201 us,
// flags+spin 320 us. The scan dependency forces column ownership -> strided
// temporal stream -> ~2.4 TB/s; nothing controllable from HIP source moved
// it. This kernel is the argmin of the 9 measured structures.
//   wave owns a 256 B-wide x H strip (lane = one float column);
//   16 strips/image x 32 images = 512 one-wave blocks (2 per CU);
//   buf[32] register prefetch (static indices; D divides H exactly);
//   zero sync, zero LDS, x read once, out written once, full-line stores.

constexpr int B = 32;
constexpr int H = 1024;
constexpr int W = 1024;            // floats per row (4 KB)
constexpr int SWF = 64;            // strip width in floats = 256 B
constexpr int NSTRIP = W / SWF;    // 16 strips per image
constexpr int NBLK = B * NSTRIP;   // 512 one-wave blocks
constexpr int D = 32;              // prefetch depth in rows; MUST divide H
static_assert(H % D == 0, "D must divide H");

__global__ __launch_bounds__(64) void cummax_stream(const float* __restrict__ x,
                                                    float* __restrict__ o) {
    const int sid = blockIdx.x;
    const int b = sid >> 4;             // image
    const int st = sid & (NSTRIP - 1);  // strip within row
    const int lane = threadIdx.x;       // 0..63 = float column within strip

    const size_t base = (size_t)b * H * W + (size_t)st * SWF + lane;
    const float* xp = x + base;
    float* op = o + base;

    float carry = -__builtin_inff();
    float buf[D];

    // prologue: prefetch rows 0..D-1
#pragma unroll
    for (int r = 0; r < D; ++r) buf[r] = xp[(size_t)r * W];

    // main: process D rows, prefetch the next D (all buf indices static)
    int hb = 0;
    for (; hb < H - D; hb += D) {
        const float* xn = xp + (size_t)(hb + D) * W;
        float* on = op + (size_t)hb * W;
#pragma unroll
        for (int r = 0; r < D; ++r) {
            float v = buf[r];
            buf[r] = xn[(size_t)r * W];       // prefetch row hb+D+r
            carry = fmaxf(carry, v);
            on[(size_t)r * W] = carry;        // store row hb+r
        }
    }

    // epilogue: last D rows (already in buf), no prefetch
    {
        float* on = op + (size_t)hb * W;
#pragma unroll
        for (int r = 0; r < D; ++r) {
            carry = fmaxf(carry, buf[r]);
            on[(size_t)r * W] = carry;
        }
    }
}

extern "C" void kernel_launch(void* const* d_in, const int* in_sizes, int n_in,
                              void* d_out, int out_size, void* d_ws, size_t ws_size,
                              hipStream_t stream) {
    const float* x = (const float*)d_in[0];
    float* out = (float*)d_out;
    cummax_stream<<<NBLK, 64, 0, stream>>>(x, out);
}